// Round 1
// baseline (7433.962 us; speedup 1.0000x reference)
//
#include <hip/hip_runtime.h>

// GRU decoder (Keras GRUCell reset_after=True path), fp32 baseline.
// B=8192 rows fully independent; each block owns BM=16 rows for all T=96
// steps, h kept transposed in LDS. Weights streamed from global (L2-resident).

#define Bdim 8192
#define Tdim 96
#define Fdim 64
#define Hdim 256
#define Cdim 768   // 3H
#define BM   16
#define XS   20    // padded LDS row stride in floats (80 B -> 16B-aligned rows)

__launch_bounds__(256)
__global__ void gru_decoder_fp32(
    const float* __restrict__ feat,       // [B,T,F]
    const float* __restrict__ init_state, // [B,H]
    const float* __restrict__ init_inp,   // [B,1]
    const float* __restrict__ Wk,         // [1+F, 3H]
    const float* __restrict__ Wr,         // [H, 3H]
    const float* __restrict__ ib,         // [3H]
    const float* __restrict__ rb,         // [3H]
    const float* __restrict__ dw,         // [H,1]
    const float* __restrict__ db,         // [1]
    float* __restrict__ out)              // [B,T,1]
{
    __shared__ __align__(16) float xT[(Fdim + 1) * XS]; // x transposed: xT[k*XS + r]
    __shared__ __align__(16) float hT[Hdim * XS];       // h transposed: hT[k*XS + r]
    __shared__ float prev_out[BM];
    __shared__ float wpart[4][BM];

    const int j    = threadIdx.x;        // column 0..255 (owns cols j, j+256, j+512)
    const int b0   = blockIdx.x * BM;
    const int lane = j & 63;
    const int wid  = j >> 6;

    // --- init h (transposed) ---
#pragma unroll
    for (int r = 0; r < BM; ++r)
        hT[j * XS + r] = init_state[(b0 + r) * Hdim + j];
    if (j < BM) prev_out[j] = init_inp[b0 + j];

    const float dwj = dw[j];
    const float db0 = db[0];
    const float bz  = ib[j]            + rb[j];
    const float brr = ib[Hdim + j]     + rb[Hdim + j];
    const float bxh = ib[2 * Hdim + j];
    const float bhh = rb[2 * Hdim + j];

    const int fr = j >> 4;   // feat-stage row 0..15
    const int fi = j & 15;   // feat-stage quad 0..15

    for (int t = 0; t < Tdim; ++t) {
        __syncthreads();  // prev iter's xT reads done; prev_out/hT updates visible

        // --- stage x = [prev_out, feat_t] transposed into LDS ---
        {
            float4 f4 = *(const float4*)&feat[((size_t)(b0 + fr) * Tdim + t) * Fdim + fi * 4];
            xT[(1 + fi * 4 + 0) * XS + fr] = f4.x;
            xT[(1 + fi * 4 + 1) * XS + fr] = f4.y;
            xT[(1 + fi * 4 + 2) * XS + fr] = f4.z;
            xT[(1 + fi * 4 + 3) * XS + fr] = f4.w;
            if (fi == 0) xT[0 * XS + fr] = prev_out[fr];
        }
        __syncthreads();

        float az[BM], ar[BM], axh[BM], ahh[BM];
#pragma unroll
        for (int r = 0; r < BM; ++r) { az[r] = bz; ar[r] = brr; axh[r] = bxh; ahh[r] = bhh; }

        // --- mx: x[B,65] @ Wk[65,768] ---
#pragma unroll 4
        for (int k = 0; k < Fdim + 1; ++k) {
            float w0 = Wk[k * Cdim + j];
            float w1 = Wk[k * Cdim + Hdim + j];
            float w2 = Wk[k * Cdim + 2 * Hdim + j];
            const float4* xv4 = (const float4*)&xT[k * XS];
            float4 xa = xv4[0], xb = xv4[1], xc = xv4[2], xd = xv4[3];
            float xv[BM] = {xa.x, xa.y, xa.z, xa.w, xb.x, xb.y, xb.z, xb.w,
                            xc.x, xc.y, xc.z, xc.w, xd.x, xd.y, xd.z, xd.w};
#pragma unroll
            for (int r = 0; r < BM; ++r) {
                az[r]  += w0 * xv[r];
                ar[r]  += w1 * xv[r];
                axh[r] += w2 * xv[r];
            }
        }

        // --- mh: h[B,256] @ Wr[256,768] ---
#pragma unroll 4
        for (int k = 0; k < Hdim; ++k) {
            float w0 = Wr[k * Cdim + j];
            float w1 = Wr[k * Cdim + Hdim + j];
            float w2 = Wr[k * Cdim + 2 * Hdim + j];
            const float4* hv4 = (const float4*)&hT[k * XS];
            float4 ha = hv4[0], hb = hv4[1], hc = hv4[2], hd = hv4[3];
            float hv[BM] = {ha.x, ha.y, ha.z, ha.w, hb.x, hb.y, hb.z, hb.w,
                            hc.x, hc.y, hc.z, hc.w, hd.x, hd.y, hd.z, hd.w};
#pragma unroll
            for (int r = 0; r < BM; ++r) {
                az[r]  += w0 * hv[r];
                ar[r]  += w1 * hv[r];
                ahh[r] += w2 * hv[r];
            }
        }
        __syncthreads();  // all hT reads for this step done

        // --- gates + state update (thread j owns h[:, j]) ---
        float hold[BM];
        {
            const float4* h4 = (const float4*)&hT[j * XS];
            float4 a = h4[0], b = h4[1], c = h4[2], d = h4[3];
            float tmp[BM] = {a.x, a.y, a.z, a.w, b.x, b.y, b.z, b.w,
                             c.x, c.y, c.z, c.w, d.x, d.y, d.z, d.w};
#pragma unroll
            for (int r = 0; r < BM; ++r) hold[r] = tmp[r];
        }
        float hnew[BM];
#pragma unroll
        for (int r = 0; r < BM; ++r) {
            float z  = 1.0f / (1.0f + __expf(-az[r]));
            float rg = 1.0f / (1.0f + __expf(-ar[r]));
            float cd = tanhf(axh[r] + rg * ahh[r]);
            hnew[r]  = z * hold[r] + (1.0f - z) * cd;
        }
        {
            float4* h4 = (float4*)&hT[j * XS];
            h4[0] = make_float4(hnew[0], hnew[1], hnew[2], hnew[3]);
            h4[1] = make_float4(hnew[4], hnew[5], hnew[6], hnew[7]);
            h4[2] = make_float4(hnew[8], hnew[9], hnew[10], hnew[11]);
            h4[3] = make_float4(hnew[12], hnew[13], hnew[14], hnew[15]);
        }

        // --- out = h_new @ dense_w + db : block-wide reduction per row ---
#pragma unroll
        for (int r = 0; r < BM; ++r) {
            float s = hnew[r] * dwj;
            s += __shfl_xor(s, 32, 64);
            s += __shfl_xor(s, 16, 64);
            s += __shfl_xor(s, 8, 64);
            s += __shfl_xor(s, 4, 64);
            s += __shfl_xor(s, 2, 64);
            s += __shfl_xor(s, 1, 64);
            if (lane == 0) wpart[wid][r] = s;
        }
        __syncthreads();  // wpart ready; hT writes done before next iter's reads
        if (j < BM) {
            float s = wpart[0][j] + wpart[1][j] + wpart[2][j] + wpart[3][j] + db0;
            out[(size_t)(b0 + j) * Tdim + t] = s;
            prev_out[j] = s;
        }
    }
}

extern "C" void kernel_launch(void* const* d_in, const int* in_sizes, int n_in,
                              void* d_out, int out_size, void* d_ws, size_t ws_size,
                              hipStream_t stream) {
    const float* feat       = (const float*)d_in[0];
    const float* init_state = (const float*)d_in[1];
    const float* init_inp   = (const float*)d_in[2];
    const float* Wk         = (const float*)d_in[3];
    const float* Wr         = (const float*)d_in[4];
    const float* ib         = (const float*)d_in[5];
    const float* rb         = (const float*)d_in[6];
    const float* dw         = (const float*)d_in[7];
    const float* db         = (const float*)d_in[8];
    float* out              = (float*)d_out;

    gru_decoder_fp32<<<Bdim / BM, 256, 0, stream>>>(
        feat, init_state, init_inp, Wk, Wr, ib, rb, dw, db, out);
}

// Round 2
// 1848.041 us; speedup vs baseline: 4.0226x; 4.0226x over previous
//
#include <hip/hip_runtime.h>

// GRU decoder, bf16-MFMA version.
// Per block: BM=32 batch rows for all T=96 steps. 8 waves, each owns 32
// h-columns x 3 gates (6 N-tiles of 16). Weights pre-swizzled into d_ws in
// MFMA B-fragment order (one coalesced dwordx4 per frag per lane).
// Wk (K=96 padded) resident in registers; Wr (K=256) streamed from L2.
// h carried fp32 in registers (C-layout is stable across steps), bf16 copy
// in LDS for next step's A-fragments.

#define Bdim 8192
#define Tdim 96
#define Fdim 64
#define Hdim 256
#define BM   32
#define XS   104   // x~ row stride (bf16 elems): 96 + 8 pad -> 208 B, 16B aligned
#define HS   264   // h row stride: 256 + 8 pad -> 528 B, 16B aligned

typedef __attribute__((ext_vector_type(8))) short s16x8;
typedef __attribute__((ext_vector_type(4))) float f32x4;

#define MFMA __builtin_amdgcn_mfma_f32_16x16x32_bf16

__device__ __forceinline__ unsigned short f2bf(float f) {
    union { float f; unsigned u; } v; v.f = f;
    unsigned r = v.u + 0x7FFFu + ((v.u >> 16) & 1u);   // round-to-nearest-even
    return (unsigned short)(r >> 16);
}

// ---- one-time (per launch) weight conversion + B-fragment swizzle ----
// layout: frag(w, kt, nt) = 64 lanes x 8 bf16; lane l holds
// B[k = kt*32 + (l>>4)*8 + j][n = (nt>>1)*256 + w*32 + (nt&1)*16 + (l&15)]
__global__ void prep_swz(const float* __restrict__ Wk, const float* __restrict__ Wr,
                         unsigned short* __restrict__ sK, unsigned short* __restrict__ sR) {
    int idx = blockIdx.x * blockDim.x + threadIdx.x;
    if (idx < 24576) {                     // Wr: 8 w * 8 kt * 6 nt * 64 lanes
        int lane = idx & 63, rest = idx >> 6;
        int nt = rest % 6; rest /= 6;
        int kt = rest % 8; int w = rest / 8;
        int q = lane >> 4, cc = lane & 15;
        int n = (nt >> 1) * 256 + w * 32 + (nt & 1) * 16 + cc;
        unsigned short* d = sR + (size_t)idx * 8;
#pragma unroll
        for (int j = 0; j < 8; ++j) {
            int k = kt * 32 + q * 8 + j;
            d[j] = f2bf(Wr[(size_t)k * 768 + n]);
        }
    } else if (idx < 24576 + 9216) {       // Wk: 8 w * 3 kt * 6 nt * 64 lanes
        int i2 = idx - 24576;
        int lane = i2 & 63, rest = i2 >> 6;
        int nt = rest % 6; rest /= 6;
        int kt = rest % 3; int w = rest / 3;
        int q = lane >> 4, cc = lane & 15;
        int n = (nt >> 1) * 256 + w * 32 + (nt & 1) * 16 + cc;
        unsigned short* d = sK + (size_t)i2 * 8;
#pragma unroll
        for (int j = 0; j < 8; ++j) {
            // x~ layout: k 0..63 = feat (Wk rows 1..64), k 64 = prev_out (Wk row 0), 65..95 = 0
            int k = kt * 32 + q * 8 + j;
            float v = (k < 64) ? Wk[(size_t)(k + 1) * 768 + n]
                               : (k == 64 ? Wk[n] : 0.0f);
            d[j] = f2bf(v);
        }
    }
}

__launch_bounds__(512, 2)
__global__ void gru_mfma(
    const float* __restrict__ feat,       // [B,T,F]
    const float* __restrict__ init_state, // [B,H]
    const float* __restrict__ init_inp,   // [B,1]
    const unsigned short* __restrict__ sK,
    const unsigned short* __restrict__ sR,
    const float* __restrict__ ib, const float* __restrict__ rb,
    const float* __restrict__ dw, const float* __restrict__ db,
    float* __restrict__ out)              // [B,T,1]
{
    __shared__ __align__(16) unsigned short xs[BM * XS]; // x~ row-major bf16
    __shared__ __align__(16) unsigned short hs[BM * HS]; // h row-major bf16
    __shared__ float wpart[8][BM];

    const int tid  = threadIdx.x;
    const int lane = tid & 63;
    const int w    = tid >> 6;     // wave 0..7: owns h-cols [w*32, w*32+32)
    const int q    = lane >> 4;    // quad
    const int c    = lane & 15;    // col within 16-tile
    const int b0   = blockIdx.x * BM;

    // zero x~ (covers the k=65..95 pad, which must stay 0)
    for (int i = tid; i < BM * XS; i += 512) xs[i] = 0;
    __syncthreads();

    // per-lane epilogue constants (col = w*32 + n2*16 + c)
    float bz[2], brr[2], bxh[2], bhh[2], dwv[2];
#pragma unroll
    for (int n2 = 0; n2 < 2; ++n2) {
        int col = w * 32 + n2 * 16 + c;
        bz[n2]  = ib[col] + rb[col];
        brr[n2] = ib[256 + col] + rb[256 + col];
        bxh[n2] = ib[512 + col];
        bhh[n2] = rb[512 + col];
        dwv[n2] = dw[col];
    }
    const float dbv = db[0];

    // h carried fp32 in registers; bf16 copy to LDS
    float hreg[2][2][4];
#pragma unroll
    for (int mt = 0; mt < 2; ++mt)
#pragma unroll
        for (int n2 = 0; n2 < 2; ++n2)
#pragma unroll
            for (int i = 0; i < 4; ++i) {
                int row = mt * 16 + q * 4 + i;
                int col = w * 32 + n2 * 16 + c;
                float v = init_state[(size_t)(b0 + row) * Hdim + col];
                hreg[mt][n2][i] = v;
                hs[row * HS + col] = f2bf(v);
            }

    // stage feat t=0 and prev_out init
    {
        int r = tid >> 4, fi = tid & 15;
        float4 f = *(const float4*)&feat[((size_t)(b0 + r) * Tdim + 0) * Fdim + fi * 4];
        ushort4 p; p.x = f2bf(f.x); p.y = f2bf(f.y); p.z = f2bf(f.z); p.w = f2bf(f.w);
        *(ushort4*)&xs[r * XS + fi * 4] = p;
    }
    if (tid < BM) xs[tid * XS + 64] = f2bf(init_inp[b0 + tid]);

    // Wk fragments resident in registers (3 kt x 6 nt x 4 VGPR = 72)
    s16x8 wk[3][6];
    {
        const unsigned short* kp = sK + (size_t)w * 3 * 6 * 512 + lane * 8;
#pragma unroll
        for (int kt = 0; kt < 3; ++kt)
#pragma unroll
            for (int nt = 0; nt < 6; ++nt)
                wk[kt][nt] = *(const s16x8*)(kp + (kt * 6 + nt) * 512);
    }
    const unsigned short* wrp = sR + (size_t)w * 8 * 6 * 512 + lane * 8;

    __syncthreads();

    for (int t = 0; t < Tdim; ++t) {
        f32x4 az[2][2], arr[2][2], axh[2][2], ahh[2][2];
#pragma unroll
        for (int mt = 0; mt < 2; ++mt)
#pragma unroll
            for (int n2 = 0; n2 < 2; ++n2) {
                az[mt][n2] = (f32x4)0.0f; arr[mt][n2] = (f32x4)0.0f;
                axh[mt][n2] = (f32x4)0.0f; ahh[mt][n2] = (f32x4)0.0f;
            }

        // ---- GEMM1: x~ @ Wk (3 K-tiles, weights in registers) ----
#pragma unroll
        for (int kt = 0; kt < 3; ++kt) {
            s16x8 a0 = *(const s16x8*)&xs[c * XS + kt * 32 + q * 8];
            s16x8 a1 = *(const s16x8*)&xs[(16 + c) * XS + kt * 32 + q * 8];
            az[0][0]  = MFMA(a0, wk[kt][0], az[0][0], 0, 0, 0);
            az[1][0]  = MFMA(a1, wk[kt][0], az[1][0], 0, 0, 0);
            az[0][1]  = MFMA(a0, wk[kt][1], az[0][1], 0, 0, 0);
            az[1][1]  = MFMA(a1, wk[kt][1], az[1][1], 0, 0, 0);
            arr[0][0] = MFMA(a0, wk[kt][2], arr[0][0], 0, 0, 0);
            arr[1][0] = MFMA(a1, wk[kt][2], arr[1][0], 0, 0, 0);
            arr[0][1] = MFMA(a0, wk[kt][3], arr[0][1], 0, 0, 0);
            arr[1][1] = MFMA(a1, wk[kt][3], arr[1][1], 0, 0, 0);
            axh[0][0] = MFMA(a0, wk[kt][4], axh[0][0], 0, 0, 0);
            axh[1][0] = MFMA(a1, wk[kt][4], axh[1][0], 0, 0, 0);
            axh[0][1] = MFMA(a0, wk[kt][5], axh[0][1], 0, 0, 0);
            axh[1][1] = MFMA(a1, wk[kt][5], axh[1][1], 0, 0, 0);
        }

        // ---- GEMM2: h @ Wr (8 K-tiles, weights streamed from L2) ----
#pragma unroll
        for (int kt = 0; kt < 8; ++kt) {
            s16x8 b[6];
#pragma unroll
            for (int nt = 0; nt < 6; ++nt)
                b[nt] = *(const s16x8*)(wrp + (size_t)(kt * 6 + nt) * 512);
            s16x8 a0 = *(const s16x8*)&hs[c * HS + kt * 32 + q * 8];
            s16x8 a1 = *(const s16x8*)&hs[(16 + c) * HS + kt * 32 + q * 8];
            az[0][0]  = MFMA(a0, b[0], az[0][0], 0, 0, 0);
            az[1][0]  = MFMA(a1, b[0], az[1][0], 0, 0, 0);
            az[0][1]  = MFMA(a0, b[1], az[0][1], 0, 0, 0);
            az[1][1]  = MFMA(a1, b[1], az[1][1], 0, 0, 0);
            arr[0][0] = MFMA(a0, b[2], arr[0][0], 0, 0, 0);
            arr[1][0] = MFMA(a1, b[2], arr[1][0], 0, 0, 0);
            arr[0][1] = MFMA(a0, b[3], arr[0][1], 0, 0, 0);
            arr[1][1] = MFMA(a1, b[3], arr[1][1], 0, 0, 0);
            ahh[0][0] = MFMA(a0, b[4], ahh[0][0], 0, 0, 0);
            ahh[1][0] = MFMA(a1, b[4], ahh[1][0], 0, 0, 0);
            ahh[0][1] = MFMA(a0, b[5], ahh[0][1], 0, 0, 0);
            ahh[1][1] = MFMA(a1, b[5], ahh[1][1], 0, 0, 0);
        }
        __syncthreads();   // S1: all LDS reads (xs, hs) of this step done

        // ---- epilogue: gates, h update, dense partials ----
        float sdense[2][4];
#pragma unroll
        for (int mt = 0; mt < 2; ++mt)
#pragma unroll
            for (int i = 0; i < 4; ++i) sdense[mt][i] = 0.0f;

#pragma unroll
        for (int mt = 0; mt < 2; ++mt)
#pragma unroll
            for (int n2 = 0; n2 < 2; ++n2)
#pragma unroll
                for (int i = 0; i < 4; ++i) {
                    float zz = 1.0f / (1.0f + __expf(-(az[mt][n2][i] + bz[n2])));
                    float rr = 1.0f / (1.0f + __expf(-(arr[mt][n2][i] + brr[n2])));
                    float cd = tanhf(axh[mt][n2][i] + bxh[n2] +
                                     rr * (ahh[mt][n2][i] + bhh[n2]));
                    float hn = zz * hreg[mt][n2][i] + (1.0f - zz) * cd;
                    hreg[mt][n2][i] = hn;
                    int row = mt * 16 + q * 4 + i;
                    int col = w * 32 + n2 * 16 + c;
                    hs[row * HS + col] = f2bf(hn);
                    sdense[mt][i] += hn * dwv[n2];
                }

        // dense: reduce over the 16 cols held across lanes c=0..15
#pragma unroll
        for (int mt = 0; mt < 2; ++mt)
#pragma unroll
            for (int i = 0; i < 4; ++i) {
                float s = sdense[mt][i];
                s += __shfl_xor(s, 1, 64);
                s += __shfl_xor(s, 2, 64);
                s += __shfl_xor(s, 4, 64);
                s += __shfl_xor(s, 8, 64);
                if (c == 0) wpart[w][mt * 16 + q * 4 + i] = s;
            }

        // stage feat for t+1 (xs cols 0..63; safe after S1)
        if (t + 1 < Tdim) {
            int r = tid >> 4, fi = tid & 15;
            float4 f = *(const float4*)&feat[((size_t)(b0 + r) * Tdim + (t + 1)) * Fdim + fi * 4];
            ushort4 p; p.x = f2bf(f.x); p.y = f2bf(f.y); p.z = f2bf(f.z); p.w = f2bf(f.w);
            *(ushort4*)&xs[r * XS + fi * 4] = p;
        }
        __syncthreads();   // S2: hs/wpart/feat writes visible

        if (tid < BM) {
            float s = dbv;
#pragma unroll
            for (int ww = 0; ww < 8; ++ww) s += wpart[ww][tid];
            out[(size_t)(b0 + tid) * Tdim + t] = s;
            xs[tid * XS + 64] = f2bf(s);   // prev_out for next step
        }
        __syncthreads();   // S3: prev_out visible
    }
}

extern "C" void kernel_launch(void* const* d_in, const int* in_sizes, int n_in,
                              void* d_out, int out_size, void* d_ws, size_t ws_size,
                              hipStream_t stream) {
    const float* feat       = (const float*)d_in[0];
    const float* init_state = (const float*)d_in[1];
    const float* init_inp   = (const float*)d_in[2];
    const float* Wk         = (const float*)d_in[3];
    const float* Wr         = (const float*)d_in[4];
    const float* ib         = (const float*)d_in[5];
    const float* rb         = (const float*)d_in[6];
    const float* dw         = (const float*)d_in[7];
    const float* db         = (const float*)d_in[8];
    float* out              = (float*)d_out;

    unsigned short* sR = (unsigned short*)d_ws;                    // 24576*16 B
    unsigned short* sK = (unsigned short*)((char*)d_ws + 24576 * 16); // 9216*16 B

    prep_swz<<<(24576 + 9216 + 255) / 256, 256, 0, stream>>>(Wk, Wr, sK, sR);
    gru_mfma<<<Bdim / BM, 512, 0, stream>>>(
        feat, init_state, init_inp, sK, sR, ib, rb, dw, db, out);
}